// Round 11
// baseline (397.065 us; speedup 1.0000x reference)
//
#include <hip/hip_runtime.h>

#define B_TOT 4096
#define S_LEN 1024
#define HID 30
#define SKIP 16
#define HLEN (S_LEN - SKIP)   // 1008
#define WARM 32               // min h2 warm-up steps for chunks >= 1

typedef float f32x4 __attribute__((ext_vector_type(4)));
typedef short bf16x8 __attribute__((ext_vector_type(8)));
typedef int   i32x4  __attribute__((ext_vector_type(4)));
typedef unsigned int u32x2 __attribute__((ext_vector_type(2)));

// ---- DPP helpers (epilogue red16 only) ----
template <int CTRL>
__device__ __forceinline__ float dppmov(float v) {
  return __int_as_float(__builtin_amdgcn_update_dpp(
      0, __float_as_int(v), CTRL, 0xF, 0xF, true));
}
template <int CTRL>
__device__ __forceinline__ float dpp_add(float v) { return v + dppmov<CTRL>(v); }
__device__ __forceinline__ float red16(float v) {
  v = dpp_add<0xB1>(v); v = dpp_add<0x4E>(v);
  v = dpp_add<0x141>(v); v = dpp_add<0x140>(v);
  return v;
}
__device__ __forceinline__ float sigmoid_fast(float z) {
  float e = __builtin_amdgcn_exp2f(z * -1.442695041f);
  return __builtin_amdgcn_rcpf(1.0f + e);
}
// v_cvt_pk_bf16_f32: two f32 -> one u32 of two bf16 (no builtin on gfx950)
__device__ __forceinline__ int cvt_pk_bf16(float a, float b) {
  int r; asm("v_cvt_pk_bf16_f32 %0, %1, %2" : "=v"(r) : "v"(a), "v"(b)); return r;
}
// split 8 f32 into hi/lo bf16 words (hi = bf16(v), lo = bf16(v - f32(hi)))
__device__ __forceinline__ void split8(const float* v, int* hw, int* lw) {
#pragma unroll
  for (int p = 0; p < 4; ++p) {
    int h = cvt_pk_bf16(v[2*p], v[2*p+1]);
    float f0 = __int_as_float(h << 16);
    float f1 = __int_as_float(h & 0xffff0000);
    lw[p] = cvt_pk_bf16(v[2*p] - f0, v[2*p+1] - f1);
    hw[p] = h;
  }
}
__device__ __forceinline__ bf16x8 frag4(const int* w) {
  return __builtin_bit_cast(bf16x8, (i32x4){w[0], w[1], w[2], w[3]});
}

// sum over the 4 q-lanes of a batch column -- pure-VALU permlane swaps
// (validated R8/R9/R10: H flows through this every step and passed).
__device__ __forceinline__ float redq(float v) {
#if __has_builtin(__builtin_amdgcn_permlane16_swap) && __has_builtin(__builtin_amdgcn_permlane32_swap)
  unsigned iv = __float_as_uint(v);
  u32x2 p = __builtin_amdgcn_permlane16_swap(iv, iv, false, false);
  float s = __uint_as_float(p[0]) + __uint_as_float(p[1]);
  unsigned is = __float_as_uint(s);
  u32x2 qq = __builtin_amdgcn_permlane32_swap(is, is, false, false);
  return __uint_as_float(qq[0]) + __uint_as_float(qq[1]);
#else
  v += __int_as_float(__builtin_amdgcn_ds_swizzle(__float_as_int(v), 0x401F));
  int l = (int)(threadIdx.x & 63);
  v += __int_as_float(__builtin_amdgcn_ds_bpermute(((l ^ 32) << 2),
                                                   __float_as_int(v)));
  return v;
#endif
}

// Time-chunked RNN scan with MFMA inner product, 8 chunks over 2 blocks.
// Lesson ledger: (R1) VGPR cap >= live set; (R4) plain bf16 Wh.h fatal ->
// split-bf16 3-product MFMA; (R5/R6) minimize wave-instrs; (R7) MFMA core
// verified; (R8) 8-chunk-in-one-512-block broke P (unresolved) -> this
// round splits 8 chunks across TWO proven 256-thr/4-wave blocks instead;
// (R9) redq off critical chain: 0 gain; (R10) 4-deep prefetch: -6%;
// remaining ~1000cyc/step is stall at 1 wave/SIMD -> R11: 2 blocks/CU =
// 2 waves/SIMD (VGPR 152x2 <= 512 fits), P partials via d_ws workspace +
// separate epilogue kernel.
//
// Wave layout: batch = lane&15 (16 batches/wave), q = lane>>4.
// Slot->unit map (shared by A and B so HW k-permutation cancels):
//   slot kk<4 -> unit 4q+kk ; kk>=4 -> unit 16+4q+(kk-4)
// D-layout: col=lane&15(batch), row=4q+reg / 16+4q+reg == same unit set
// -> sigmoid output feeds next step's B-operand entirely IN-LANE.
//
// Grid 512: block = (batch-group g = bid>>1, half = bid&1). 4 chunk-waves
// per block. Output boundaries: half0 {16,160,288,408,520},
// half1 {520,648,776,900,1024} (spans %4==0; warm 32-56 steps >= the
// validated 32; contraction ~0.35/step -> state err <1e-14).
__global__ __launch_bounds__(256) void mminet_scan(
    const float* __restrict__ x,   const float* __restrict__ var,
    const float* __restrict__ s0,
    const float* __restrict__ W1,  const float* __restrict__ b1,
    const float* __restrict__ Wx,  const float* __restrict__ Wh,
    const float* __restrict__ W2,  const float* __restrict__ b2,
    float* __restrict__ Hout, float* __restrict__ Pws)
{
  __shared__ float Pred[4][16];

  const int tid   = threadIdx.x;
  const int l     = tid & 63;
  const int cl    = tid >> 6;                // local chunk / wave id (0..3)
  const int half  = blockIdx.x & 1;
  const int g     = blockIdx.x >> 1;         // batch group
  const int q     = l >> 4;                  // k-block / row-subblock
  const int c     = l & 15;                  // batch column
  const int b     = g * 16 + c;

  const int ob = (half == 0)
      ? (cl == 0 ? 16  : cl == 1 ? 160 : cl == 2 ? 288 : 408)
      : (cl == 0 ? 520 : cl == 1 ? 648 : cl == 2 ? 776 : 900);
  const int oe = (half == 0)
      ? (cl == 0 ? 160 : cl == 1 ? 288 : cl == 2 ? 408 : 520)
      : (cl == 0 ? 648 : cl == 1 ? 776 : cl == 2 ? 900 : 1024);
  const bool first = (half == 0) && (cl == 0);
  const int ps = first ? SKIP : ((ob - WARM) & ~31);  // %32==0 for prescan

  const float v0 = var[b*4+0], v1 = var[b*4+1], v2 = var[b*4+2], v3 = var[b*4+3];

  // ---- per-lane row constants for owned D-rows (== units) ----
  float wx0[8], wx1[8], wx2[8], cva[8], w1a[8], w2a[8], rc[8], s1[8];
#pragma unroll
  for (int i = 0; i < 8; ++i) {
    const int row = (i < 4) ? (4*q + i) : (16 + 4*q + (i - 4));
    if (row < HID) {
      wx0[i] = Wx[row*7+0]; wx1[i] = Wx[row*7+1]; wx2[i] = Wx[row*7+2];
      cva[i] = Wx[row*7+3]*v0 + Wx[row*7+4]*v1 + Wx[row*7+5]*v2 + Wx[row*7+6]*v3;
      w1a[i] = W1[row]; w2a[i] = W2[row];
      rc[i]  = 5.0f * (float)(row + 1) / 30.0f;
      s1[i]  = s0[b*HID + row];
    } else {
      wx0[i]=wx1[i]=wx2[i]=cva[i]=w1a[i]=w2a[i]=s1[i]=0.f; rc[i]=1.0f;
    }
  }

  // ---- A fragments (Wh, split-bf16), rows c and 16+c ----
  float a1v[8], a2v[8];
#pragma unroll
  for (int kk = 0; kk < 8; ++kk) {
    const int u = (kk < 4) ? (4*q + kk) : (16 + 4*q + (kk - 4));
    a1v[kk] = (u < HID) ? Wh[c*HID + u] : 0.f;
    a2v[kk] = (u < HID && (16 + c) < HID) ? Wh[(16+c)*HID + u] : 0.f;
  }
  int t0[4], t1[4], t2[4], t3[4];
  split8(a1v, t0, t1); split8(a2v, t2, t3);
  const bf16x8 A1h = frag4(t0), A1l = frag4(t1);
  const bf16x8 A2h = frag4(t2), A2l = frag4(t3);

  const float hcst = W1[30]*v0 + W1[31]*v1 + W1[32]*v2 + W1[33]*v3 + b1[0];
  const float hc2  = hcst + b2[0];

  float sw = 0.f;
#pragma unroll
  for (int i = 0; i < 8; ++i) sw += w2a[i];
  const float sumW2 = redq(sw);

  const float4* xb = (const float4*)(x + (size_t)b * S_LEN * 4);

  bf16x8 Bhi, Blo;
  auto packB = [&](const float* hv) {
    int bh[4], bl[4];
    split8(hv, bh, bl);
    Bhi = frag4(bh); Blo = frag4(bl);
  };

  // one RNN step for 16 batches: 6 independent MFMA + VALU epilogue
  auto dostep = [&](const float4 xq) -> float {
#pragma unroll
    for (int i = 0; i < 8; ++i)
      s1[i] = __builtin_amdgcn_fmed3f(s1[i] + xq.y, -rc[i], rc[i]);
    f32x4 zi0, zi1;
#pragma unroll
    for (int i = 0; i < 4; ++i) {
      zi0[i] = cva[i]   + wx0[i]*xq.x   + wx1[i]*xq.z   + wx2[i]*xq.w;
      zi1[i] = cva[i+4] + wx0[i+4]*xq.x + wx1[i+4]*xq.z + wx2[i+4]*xq.w;
    }
    const f32x4 zz = {0.f, 0.f, 0.f, 0.f};
    f32x4 a0 = __builtin_amdgcn_mfma_f32_16x16x32_bf16(A1h, Bhi, zi0, 0, 0, 0);
    f32x4 b0 = __builtin_amdgcn_mfma_f32_16x16x32_bf16(A1l, Bhi, zz,  0, 0, 0);
    f32x4 c0 = __builtin_amdgcn_mfma_f32_16x16x32_bf16(A1h, Blo, zz,  0, 0, 0);
    f32x4 a1 = __builtin_amdgcn_mfma_f32_16x16x32_bf16(A2h, Bhi, zi1, 0, 0, 0);
    f32x4 b1v= __builtin_amdgcn_mfma_f32_16x16x32_bf16(A2l, Bhi, zz,  0, 0, 0);
    f32x4 c1 = __builtin_amdgcn_mfma_f32_16x16x32_bf16(A2h, Blo, zz,  0, 0, 0);
    f32x4 z0 = (a0 + b0) + c0;
    f32x4 z1 = (a1 + b1v) + c1;
    float hv[8];
#pragma unroll
    for (int i = 0; i < 4; ++i) {
      hv[i]     = sigmoid_fast(z0[i]);
      hv[4 + i] = sigmoid_fast(z1[i]);
    }
    packB(hv);                                 // B for NEXT step, in-lane
    float hp = 0.f;
#pragma unroll
    for (int i = 0; i < 8; ++i)
      hp = fmaf(w1a[i], s1[i], fmaf(w2a[i], hv[i], hp));
    return redq(hp);                           // + hc2 by caller
  };

  if (first) {
    // ---- t = 0 prologue (exact reference init) ----
    float4 xv = xb[0];
#pragma unroll
    for (int i = 0; i < 8; ++i)
      s1[i] = __builtin_amdgcn_fmed3f(s1[i] + xv.y, -rc[i], rc[i]);
    float hh = 0.f;
#pragma unroll
    for (int i = 0; i < 8; ++i) hh = fmaf(w1a[i], s1[i], hh);
    const float Hh0  = redq(hh) + hcst;
    const float hpre = (xv.x - Hh0) / sumW2;   // uniform initial h2
    float hv[8];
#pragma unroll
    for (int i = 0; i < 8; ++i) {
      const int row = (i < 4) ? (4*q + i) : (16 + 4*q + (i - 4));
      float rs = 0.f;
      if (row < HID)
        for (int u2 = 0; u2 < HID; ++u2) rs += Wh[row*HID + u2];
      float z = cva[i] + wx0[i]*xv.x + wx1[i]*xv.z + wx2[i]*xv.w + rs*hpre;
      hv[i] = sigmoid_fast(z);
    }
    packB(hv);
    // ---- t = 1..15 : recurrence only ----
    for (int t = 1; t < SKIP; ++t) (void)dostep(xb[t]);
  } else {
    // ---- s1-only exact prescan over [0, ps): 32-deep pipelined ----
    const float* xf = x + (size_t)b * S_LEN * 4;
    float dc[32], dn[32];
#pragma unroll
    for (int u = 0; u < 32; ++u) dc[u] = xf[u*4 + 1];
    for (int t = 0; t < ps; t += 32) {
      const bool more = (t + 32 < ps);          // wave-uniform
      if (more) {
#pragma unroll
        for (int u = 0; u < 32; ++u) dn[u] = xf[(t + 32 + u)*4 + 1];
      }
#pragma unroll
      for (int u = 0; u < 32; ++u) {
#pragma unroll
        for (int i = 0; i < 8; ++i)
          s1[i] = __builtin_amdgcn_fmed3f(s1[i] + dc[u], -rc[i], rc[i]);
      }
      if (more) {
#pragma unroll
        for (int u = 0; u < 32; ++u) dc[u] = dn[u];
      }
    }
    // h2 warm-up handled by the unified loop below (t in [ps, ob))
    float hv[8];
#pragma unroll
    for (int i = 0; i < 8; ++i) hv[i] = 0.5f;
    packB(hv);
  }

  // ==== unified warm+output loop: t in [ps, oe), 4-block, 4-deep
  // prefetch (proven R10). P pairs only for s >= ob and s > SKIP;
  // stores only when t >= ob (block-uniform; ps, ob both %4==0).
  float P = 0.f, Hprev = 0.f, Bprev = 0.f;
  float4 xc0 = xb[ps+0], xc1 = xb[ps+1], xc2 = xb[ps+2], xc3 = xb[ps+3];

  for (int t = ps; t < oe; t += 4) {
    const int tn = (t + 4 < oe) ? (t + 4) : t;  // uniform
    float4 xn0 = xb[tn+0], xn1 = xb[tn+1], xn2 = xb[tn+2], xn3 = xb[tn+3];

    float hq0, hq1, hq2, hq3;
    {
      float Ht = dostep(xc0) + hc2;
      if (t + 0 > SKIP && t + 0 >= ob) P += (xc0.x - Bprev) * (Ht + Hprev);
      Hprev = Ht; Bprev = xc0.x; hq0 = Ht;
    }
    {
      float Ht = dostep(xc1) + hc2;
      if (t + 1 > SKIP && t + 1 >= ob) P += (xc1.x - Bprev) * (Ht + Hprev);
      Hprev = Ht; Bprev = xc1.x; hq1 = Ht;
    }
    {
      float Ht = dostep(xc2) + hc2;
      if (t + 2 > SKIP && t + 2 >= ob) P += (xc2.x - Bprev) * (Ht + Hprev);
      Hprev = Ht; Bprev = xc2.x; hq2 = Ht;
    }
    {
      float Ht = dostep(xc3) + hc2;
      if (t + 3 > SKIP && t + 3 >= ob) P += (xc3.x - Bprev) * (Ht + Hprev);
      Hprev = Ht; Bprev = xc3.x; hq3 = Ht;
    }
    if (t >= ob && l < 16) {                   // q==0 lane stores batch c
      *(float4*)(Hout + (size_t)b * HLEN + (t - SKIP)) =
          make_float4(hq0, hq1, hq2, hq3);
    }
    xc0 = xn0; xc1 = xn1; xc2 = xn2; xc3 = xn3;
  }

  // ---- per-block P reduction -> workspace (both slots overwritten) ----
  if (l < 16) Pred[cl][c] = P;
  __syncthreads();
  if (tid < 16) {
    const int bb = g * 16 + tid;
    Pws[bb * 2 + half] =
        Pred[0][tid] + Pred[1][tid] + Pred[2][tid] + Pred[3][tid];
  }
}

// ==== epilogue kernel: 16 groups of 16 lanes per block, one batch each ====
__global__ __launch_bounds__(256) void mminet_mlp(
    const float* __restrict__ var, const float* __restrict__ amps,
    const float* __restrict__ Wm1, const float* __restrict__ bm1,
    const float* __restrict__ Wm2, const float* __restrict__ bm2,
    const float* __restrict__ Wm3, const float* __restrict__ bm3,
    const float* __restrict__ Pws, float* __restrict__ out2)
{
  __shared__ float mlpbuf[16][64];
  const int tid = threadIdx.x;
  const int li  = tid & 15;
  const int g   = tid >> 4;                    // 0..15
  const int be  = blockIdx.x * 16 + g;

  const float Ptot = Pws[be*2 + 0] + Pws[be*2 + 1];
  const float e0 = var[be*4+0], e1 = var[be*4+1], e2 = var[be*4+2], e3 = var[be*4+3];
  const float am0 = amps[be*2+0], am1 = amps[be*2+1];

  float Pp = Ptot * 0.5f * am0 * am1;
  Pp *= __builtin_amdgcn_exp2f(e0 * 3.321928095f);     // * 10^var0
  Pp = fmaxf(Pp, 1e-12f);
  const float Pcv = __builtin_amdgcn_logf(Pp) * 0.30102999566f;  // log10

  float* hs = &mlpbuf[g][0];
#pragma unroll
  for (int qq = 0; qq < 4; ++qq) {
    const int n = li + 16 * qq;
    const float* wr = Wm1 + n * 5;
    float h1v = bm1[n] + wr[0]*e0 + wr[1]*e1 + wr[2]*e2 + wr[3]*e3 + wr[4]*Pcv;
    hs[n] = fmaxf(h1v, 0.f);                   // wave-synchronous in group
  }
  const int m0 = li, m1 = li + 16;
  const float4* h1v4 = (const float4*)hs;
  const float4* w2a4 = (const float4*)(Wm2 + m0 * 64);
  const float4* w2b4 = (const float4*)(Wm2 + m1 * 64);
  float zz0 = bm2[m0], zz1 = bm2[m1];
#pragma unroll
  for (int qq = 0; qq < 16; ++qq) {
    float4 hh = h1v4[qq];
    float4 wa = w2a4[qq], wb = w2b4[qq];
    zz0 += wa.x*hh.x + wa.y*hh.y + wa.z*hh.z + wa.w*hh.w;
    zz1 += wb.x*hh.x + wb.y*hh.y + wb.z*hh.z + wb.w*hh.w;
  }
  float sp = Wm3[m0] * fmaxf(zz0, 0.f) + Wm3[m1] * fmaxf(zz1, 0.f);
  sp = red16(sp);
  if (li == 0) out2[be] = Pcv + sp + bm3[0];
}

extern "C" void kernel_launch(void* const* d_in, const int* in_sizes, int n_in,
                              void* d_out, int out_size, void* d_ws, size_t ws_size,
                              hipStream_t stream)
{
  const float* x    = (const float*)d_in[0];
  const float* var  = (const float*)d_in[1];
  const float* amps = (const float*)d_in[2];
  const float* s0   = (const float*)d_in[3];
  const float* W1   = (const float*)d_in[4];
  const float* b1   = (const float*)d_in[5];
  const float* Wx   = (const float*)d_in[6];
  const float* Wh   = (const float*)d_in[7];
  const float* W2   = (const float*)d_in[8];
  const float* b2   = (const float*)d_in[9];
  const float* Wm1  = (const float*)d_in[10];
  const float* bm1  = (const float*)d_in[11];
  const float* Wm2  = (const float*)d_in[12];
  const float* bm2  = (const float*)d_in[13];
  const float* Wm3  = (const float*)d_in[14];
  const float* bm3  = (const float*)d_in[15];
  // d_in[16] = n_init (compile-time 16)

  float* Hout = (float*)d_out;
  float* out2 = (float*)d_out + (size_t)B_TOT * HLEN;
  float* Pws  = (float*)d_ws;                  // 4096*2 floats = 32 KB

  mminet_scan<<<(B_TOT / 16) * 2, 256, 0, stream>>>(
      x, var, s0, W1, b1, Wx, Wh, W2, b2, Hout, Pws);
  mminet_mlp<<<B_TOT / 16, 256, 0, stream>>>(
      var, amps, Wm1, bm1, Wm2, bm2, Wm3, bm3, Pws, out2);
}

// Round 12
// 333.028 us; speedup vs baseline: 1.1923x; 1.1923x over previous
//
#include <hip/hip_runtime.h>

#define B_TOT 4096
#define S_LEN 1024
#define HID 30
#define SKIP 16
#define HLEN (S_LEN - SKIP)   // 1008
#define WARM 32               // min h2 warm-up steps for non-first chunks

typedef float f32x16 __attribute__((ext_vector_type(16)));
typedef short bf16x8 __attribute__((ext_vector_type(8)));
typedef int   i32x4  __attribute__((ext_vector_type(4)));
typedef unsigned int u32x2 __attribute__((ext_vector_type(2)));

// ---- DPP helpers (epilogue red16 only) ----
template <int CTRL>
__device__ __forceinline__ float dppmov(float v) {
  return __int_as_float(__builtin_amdgcn_update_dpp(
      0, __float_as_int(v), CTRL, 0xF, 0xF, true));
}
template <int CTRL>
__device__ __forceinline__ float dpp_add(float v) { return v + dppmov<CTRL>(v); }
__device__ __forceinline__ float red16(float v) {
  v = dpp_add<0xB1>(v); v = dpp_add<0x4E>(v);
  v = dpp_add<0x141>(v); v = dpp_add<0x140>(v);
  return v;
}
__device__ __forceinline__ float sigmoid_fast(float z) {
  float e = __builtin_amdgcn_exp2f(z * -1.442695041f);
  return __builtin_amdgcn_rcpf(1.0f + e);
}
// v_cvt_pk_bf16_f32: two f32 -> one u32 of two bf16 (no builtin on gfx950)
__device__ __forceinline__ int cvt_pk_bf16(float a, float b) {
  int r; asm("v_cvt_pk_bf16_f32 %0, %1, %2" : "=v"(r) : "v"(a), "v"(b)); return r;
}
// split 8 f32 into hi/lo bf16 words (hi = bf16(v), lo = bf16(v - f32(hi)))
__device__ __forceinline__ void split8(const float* v, int* hw, int* lw) {
#pragma unroll
  for (int p = 0; p < 4; ++p) {
    int h = cvt_pk_bf16(v[2*p], v[2*p+1]);
    float f0 = __int_as_float(h << 16);
    float f1 = __int_as_float(h & 0xffff0000);
    lw[p] = cvt_pk_bf16(v[2*p] - f0, v[2*p+1] - f1);
    hw[p] = h;
  }
}
__device__ __forceinline__ bf16x8 frag4(const int* w) {
  return __builtin_bit_cast(bf16x8, (i32x4){w[0], w[1], w[2], w[3]});
}

// exchange lane l <-> l^32 and add (the two row-halves of one batch col)
__device__ __forceinline__ float redh(float v) {
#if __has_builtin(__builtin_amdgcn_permlane32_swap)
  unsigned iv = __float_as_uint(v);
  u32x2 qq = __builtin_amdgcn_permlane32_swap(iv, iv, false, false);
  return __uint_as_float(qq[0]) + __uint_as_float(qq[1]);
#else
  int l = (int)(threadIdx.x & 63);
  v += __int_as_float(__builtin_amdgcn_ds_bpermute(((l ^ 32) << 2),
                                                   __float_as_int(v)));
  return v;
#endif
}

// Time-chunked RNN scan, 32x32x16 MFMA, 32 batches/wave, 8 chunks/batch.
// Lesson ledger: (R1) VGPR cap >= live set; (R4) plain bf16 Wh.h fatal ->
// split-bf16 3-product; (R5/R6) minimize wave-instrs; (R7) 16x16 MFMA core
// verified; (R8/R11) 2 waves/SIMD co-residency UNOBTAINABLE at this
// footprint (R11: blocks serialized, occ 9.6%) -> accept 1 wave/SIMD and
// instead HALVE SERIAL STEPS: 32x32x16 serves 32 batches/wave; 8 chunks
// via R11's correctness-proven 2-block + Pws split -> 1024 waves = 1/SIMD
// with ~170 steps/wave (vs 288).
//
// Wave layout: batch col cb = lane&31, hi = lane>>5.
// D (m74/m101-verified): col=lane&31, row R(r)=(r&3)+8*(r>>2)+4*hi, r=0..15.
// k-unit maps (same for A and B so the HW k-permutation cancels, as
// empirically verified for the 16x16 analog in R7):
//   k-half 1 slot (j,hi) -> unit R(j);  k-half 2 -> unit 16+R(j).
// Since {R(0..7), 16+R(0..7)} == lane's D-row set, the sigmoid output
// feeds next step's B fragments ENTIRELY IN-LANE:
//   B1 = pack(hv[0..7]), B2 = pack(hv[8..15]).
// A row = lane&31 (rows 30,31 and units 30,31 zeroed).
//
// Grid 256 scan-blocks: block = (group g = bid>>1, half = bid&1), 4 waves.
// Output boundaries: half0 {16,160,288,408,520}, half1 {520,648,776,900,
// 1024} (spans %4==0). Non-first chunks: exact s1-only prescan [0,ps),
// ps=(ob-32)&~31, then 32-56 full warm-up steps (contraction ~0.35/step,
// state err <1e-14; validated R2/R5/R6/R7/R9/R10/R11).
__global__ __launch_bounds__(256) void mminet_scan(
    const float* __restrict__ x,   const float* __restrict__ var,
    const float* __restrict__ s0,
    const float* __restrict__ W1,  const float* __restrict__ b1,
    const float* __restrict__ Wx,  const float* __restrict__ Wh,
    const float* __restrict__ W2,  const float* __restrict__ b2,
    float* __restrict__ Hout, float* __restrict__ Pws)
{
  __shared__ float Pred[4][32];

  const int tid   = threadIdx.x;
  const int l     = tid & 63;
  const int cl    = tid >> 6;                // local chunk / wave id (0..3)
  const int half  = blockIdx.x & 1;
  const int g     = blockIdx.x >> 1;         // batch group (32 batches)
  const int hi    = l >> 5;                  // row-half
  const int cb    = l & 31;                  // batch column
  const int b     = g * 32 + cb;

  const int ob = (half == 0)
      ? (cl == 0 ? 16  : cl == 1 ? 160 : cl == 2 ? 288 : 408)
      : (cl == 0 ? 520 : cl == 1 ? 648 : cl == 2 ? 776 : 900);
  const int oe = (half == 0)
      ? (cl == 0 ? 160 : cl == 1 ? 288 : cl == 2 ? 408 : 520)
      : (cl == 0 ? 648 : cl == 1 ? 776 : cl == 2 ? 900 : 1024);
  const bool first = (half == 0) && (cl == 0);
  const int ps = first ? SKIP : ((ob - WARM) & ~31);  // %32==0

  const float v0 = var[b*4+0], v1 = var[b*4+1], v2 = var[b*4+2], v3 = var[b*4+3];

  // ---- per-lane row constants for owned D-rows R(r) ----
  float wx0[16], wx1[16], wx2[16], cva[16], w1a[16], w2a[16], rc[16], s1[16];
#pragma unroll
  for (int r = 0; r < 16; ++r) {
    const int row = (r & 3) + 8 * (r >> 2) + 4 * hi;
    if (row < HID) {
      wx0[r] = Wx[row*7+0]; wx1[r] = Wx[row*7+1]; wx2[r] = Wx[row*7+2];
      cva[r] = Wx[row*7+3]*v0 + Wx[row*7+4]*v1 + Wx[row*7+5]*v2 + Wx[row*7+6]*v3;
      w1a[r] = W1[row]; w2a[r] = W2[row];
      rc[r]  = 5.0f * (float)(row + 1) / 30.0f;
      s1[r]  = s0[b*HID + row];
    } else {
      wx0[r]=wx1[r]=wx2[r]=cva[r]=w1a[r]=w2a[r]=s1[r]=0.f; rc[r]=1.0f;
    }
  }

  // ---- A fragments (Wh, split-bf16), row = cb, k-units R(j)/16+R(j) ----
  float a1v[8], a2v[8];
#pragma unroll
  for (int j = 0; j < 8; ++j) {
    const int u1 = (j & 3) + 8 * (j >> 2) + 4 * hi;   // 0..15
    const int u2 = 16 + u1;                           // 16..31
    a1v[j] = (cb < HID) ? Wh[cb*HID + u1] : 0.f;
    a2v[j] = (cb < HID && u2 < HID) ? Wh[cb*HID + u2] : 0.f;
  }
  int t0[4], t1[4], t2[4], t3[4];
  split8(a1v, t0, t1); split8(a2v, t2, t3);
  const bf16x8 A1h = frag4(t0), A1l = frag4(t1);
  const bf16x8 A2h = frag4(t2), A2l = frag4(t3);

  const float hcst = W1[30]*v0 + W1[31]*v1 + W1[32]*v2 + W1[33]*v3 + b1[0];
  const float hc2  = hcst + b2[0];

  float sw = 0.f;
#pragma unroll
  for (int r = 0; r < 16; ++r) sw += w2a[r];
  const float sumW2 = redh(sw);

  const float4* xb = (const float4*)(x + (size_t)b * S_LEN * 4);

  bf16x8 B1h, B1l, B2h, B2l;
  auto packB = [&](const float* hv) {
    int bh[4], bl[4];
    split8(hv, bh, bl);      B1h = frag4(bh); B1l = frag4(bl);
    split8(hv + 8, bh, bl);  B2h = frag4(bh); B2l = frag4(bl);
  };

  // one RNN step for 32 batches: 6 independent 32x32x16 MFMAs + VALU
  auto dostep = [&](const float4 xq) -> float {
#pragma unroll
    for (int r = 0; r < 16; ++r)
      s1[r] = __builtin_amdgcn_fmed3f(s1[r] + xq.y, -rc[r], rc[r]);
    f32x16 zi, zz;
#pragma unroll
    for (int r = 0; r < 16; ++r) {
      zi[r] = cva[r] + wx0[r]*xq.x + wx1[r]*xq.z + wx2[r]*xq.w;
      zz[r] = 0.f;
    }
    f32x16 a0 = __builtin_amdgcn_mfma_f32_32x32x16_bf16(A1h, B1h, zi, 0, 0, 0);
    f32x16 a1 = __builtin_amdgcn_mfma_f32_32x32x16_bf16(A2h, B2h, zz, 0, 0, 0);
    f32x16 b0 = __builtin_amdgcn_mfma_f32_32x32x16_bf16(A1l, B1h, zz, 0, 0, 0);
    f32x16 b1v= __builtin_amdgcn_mfma_f32_32x32x16_bf16(A2l, B2h, zz, 0, 0, 0);
    f32x16 c0 = __builtin_amdgcn_mfma_f32_32x32x16_bf16(A1h, B1l, zz, 0, 0, 0);
    f32x16 c1 = __builtin_amdgcn_mfma_f32_32x32x16_bf16(A2h, B2l, zz, 0, 0, 0);
    f32x16 z = ((a0 + a1) + (b0 + b1v)) + (c0 + c1);
    float hv[16];
#pragma unroll
    for (int r = 0; r < 16; ++r) hv[r] = sigmoid_fast(z[r]);
    packB(hv);                                 // B for NEXT step, in-lane
    float hp = 0.f;
#pragma unroll
    for (int r = 0; r < 16; ++r)
      hp = fmaf(w1a[r], s1[r], fmaf(w2a[r], hv[r], hp));
    return redh(hp);                           // + hc2 by caller
  };

  if (first) {
    // ---- t = 0 prologue (exact reference init) ----
    float4 xv = xb[0];
#pragma unroll
    for (int r = 0; r < 16; ++r)
      s1[r] = __builtin_amdgcn_fmed3f(s1[r] + xv.y, -rc[r], rc[r]);
    float hh = 0.f;
#pragma unroll
    for (int r = 0; r < 16; ++r) hh = fmaf(w1a[r], s1[r], hh);
    const float Hh0  = redh(hh) + hcst;
    const float hpre = (xv.x - Hh0) / sumW2;   // uniform initial h2
    float hv[16];
#pragma unroll
    for (int r = 0; r < 16; ++r) {
      const int row = (r & 3) + 8 * (r >> 2) + 4 * hi;
      float rs = 0.f;
      if (row < HID)
        for (int u = 0; u < HID; ++u) rs += Wh[row*HID + u];
      float z = cva[r] + wx0[r]*xv.x + wx1[r]*xv.z + wx2[r]*xv.w + rs*hpre;
      hv[r] = sigmoid_fast(z);
    }
    packB(hv);
    // ---- t = 1..15 : recurrence only ----
    for (int t = 1; t < SKIP; ++t) (void)dostep(xb[t]);
  } else {
    // ---- s1-only exact prescan over [0, ps): 32-deep pipelined ----
    const float* xf = x + (size_t)b * S_LEN * 4;
    float dc[32], dn[32];
#pragma unroll
    for (int u = 0; u < 32; ++u) dc[u] = xf[u*4 + 1];
    for (int t = 0; t < ps; t += 32) {
      const bool more = (t + 32 < ps);          // wave-uniform
      if (more) {
#pragma unroll
        for (int u = 0; u < 32; ++u) dn[u] = xf[(t + 32 + u)*4 + 1];
      }
#pragma unroll
      for (int u = 0; u < 32; ++u) {
#pragma unroll
        for (int r = 0; r < 16; ++r)
          s1[r] = __builtin_amdgcn_fmed3f(s1[r] + dc[u], -rc[r], rc[r]);
      }
      if (more) {
#pragma unroll
        for (int u = 0; u < 32; ++u) dc[u] = dn[u];
      }
    }
    // h2 warm-up handled by the unified loop below (t in [ps, ob))
    float hv[16];
#pragma unroll
    for (int r = 0; r < 16; ++r) hv[r] = 0.5f;
    packB(hv);
  }

  // ==== unified warm+output loop: t in [ps, oe), 4-block, 4-deep
  // prefetch (proven R10/R11). P pairs only for s >= ob and s > SKIP;
  // stores only when t >= ob (block-uniform; ps, ob both %4==0).
  float P = 0.f, Hprev = 0.f, Bprev = 0.f;
  float4 xc0 = xb[ps+0], xc1 = xb[ps+1], xc2 = xb[ps+2], xc3 = xb[ps+3];

  for (int t = ps; t < oe; t += 4) {
    const int tn = (t + 4 < oe) ? (t + 4) : t;  // uniform
    float4 xn0 = xb[tn+0], xn1 = xb[tn+1], xn2 = xb[tn+2], xn3 = xb[tn+3];

    float hq0, hq1, hq2, hq3;
    {
      float Ht = dostep(xc0) + hc2;
      if (t + 0 > SKIP && t + 0 >= ob) P += (xc0.x - Bprev) * (Ht + Hprev);
      Hprev = Ht; Bprev = xc0.x; hq0 = Ht;
    }
    {
      float Ht = dostep(xc1) + hc2;
      if (t + 1 > SKIP && t + 1 >= ob) P += (xc1.x - Bprev) * (Ht + Hprev);
      Hprev = Ht; Bprev = xc1.x; hq1 = Ht;
    }
    {
      float Ht = dostep(xc2) + hc2;
      if (t + 2 > SKIP && t + 2 >= ob) P += (xc2.x - Bprev) * (Ht + Hprev);
      Hprev = Ht; Bprev = xc2.x; hq2 = Ht;
    }
    {
      float Ht = dostep(xc3) + hc2;
      if (t + 3 > SKIP && t + 3 >= ob) P += (xc3.x - Bprev) * (Ht + Hprev);
      Hprev = Ht; Bprev = xc3.x; hq3 = Ht;
    }
    if (t >= ob && l < 32) {                   // hi==0 lane stores batch cb
      *(float4*)(Hout + (size_t)b * HLEN + (t - SKIP)) =
          make_float4(hq0, hq1, hq2, hq3);
    }
    xc0 = xn0; xc1 = xn1; xc2 = xn2; xc3 = xn3;
  }

  // ---- per-block P reduction -> workspace (both slots overwritten) ----
  if (l < 32) Pred[cl][cb] = P;
  __syncthreads();
  if (tid < 32) {
    const int bb = g * 32 + tid;
    Pws[bb * 2 + half] =
        Pred[0][tid] + Pred[1][tid] + Pred[2][tid] + Pred[3][tid];
  }
}

// ==== epilogue kernel: 16 groups of 16 lanes per block, one batch each ====
__global__ __launch_bounds__(256) void mminet_mlp(
    const float* __restrict__ var, const float* __restrict__ amps,
    const float* __restrict__ Wm1, const float* __restrict__ bm1,
    const float* __restrict__ Wm2, const float* __restrict__ bm2,
    const float* __restrict__ Wm3, const float* __restrict__ bm3,
    const float* __restrict__ Pws, float* __restrict__ out2)
{
  __shared__ float mlpbuf[16][64];
  const int tid = threadIdx.x;
  const int li  = tid & 15;
  const int g   = tid >> 4;                    // 0..15
  const int be  = blockIdx.x * 16 + g;

  const float Ptot = Pws[be*2 + 0] + Pws[be*2 + 1];
  const float e0 = var[be*4+0], e1 = var[be*4+1], e2 = var[be*4+2], e3 = var[be*4+3];
  const float am0 = amps[be*2+0], am1 = amps[be*2+1];

  float Pp = Ptot * 0.5f * am0 * am1;
  Pp *= __builtin_amdgcn_exp2f(e0 * 3.321928095f);     // * 10^var0
  Pp = fmaxf(Pp, 1e-12f);
  const float Pcv = __builtin_amdgcn_logf(Pp) * 0.30102999566f;  // log10

  float* hs = &mlpbuf[g][0];
#pragma unroll
  for (int qq = 0; qq < 4; ++qq) {
    const int n = li + 16 * qq;
    const float* wr = Wm1 + n * 5;
    float h1v = bm1[n] + wr[0]*e0 + wr[1]*e1 + wr[2]*e2 + wr[3]*e3 + wr[4]*Pcv;
    hs[n] = fmaxf(h1v, 0.f);                   // wave-synchronous in group
  }
  const int m0 = li, m1 = li + 16;
  const float4* h1v4 = (const float4*)hs;
  const float4* w2a4 = (const float4*)(Wm2 + m0 * 64);
  const float4* w2b4 = (const float4*)(Wm2 + m1 * 64);
  float zz0 = bm2[m0], zz1 = bm2[m1];
#pragma unroll
  for (int qq = 0; qq < 16; ++qq) {
    float4 hh = h1v4[qq];
    float4 wa = w2a4[qq], wb = w2b4[qq];
    zz0 += wa.x*hh.x + wa.y*hh.y + wa.z*hh.z + wa.w*hh.w;
    zz1 += wb.x*hh.x + wb.y*hh.y + wb.z*hh.z + wb.w*hh.w;
  }
  float sp = Wm3[m0] * fmaxf(zz0, 0.f) + Wm3[m1] * fmaxf(zz1, 0.f);
  sp = red16(sp);
  if (li == 0) out2[be] = Pcv + sp + bm3[0];
}

extern "C" void kernel_launch(void* const* d_in, const int* in_sizes, int n_in,
                              void* d_out, int out_size, void* d_ws, size_t ws_size,
                              hipStream_t stream)
{
  const float* x    = (const float*)d_in[0];
  const float* var  = (const float*)d_in[1];
  const float* amps = (const float*)d_in[2];
  const float* s0   = (const float*)d_in[3];
  const float* W1   = (const float*)d_in[4];
  const float* b1   = (const float*)d_in[5];
  const float* Wx   = (const float*)d_in[6];
  const float* Wh   = (const float*)d_in[7];
  const float* W2   = (const float*)d_in[8];
  const float* b2   = (const float*)d_in[9];
  const float* Wm1  = (const float*)d_in[10];
  const float* bm1  = (const float*)d_in[11];
  const float* Wm2  = (const float*)d_in[12];
  const float* bm2  = (const float*)d_in[13];
  const float* Wm3  = (const float*)d_in[14];
  const float* bm3  = (const float*)d_in[15];
  // d_in[16] = n_init (compile-time 16)

  float* Hout = (float*)d_out;
  float* out2 = (float*)d_out + (size_t)B_TOT * HLEN;
  float* Pws  = (float*)d_ws;                  // 4096*2 floats = 32 KB

  mminet_scan<<<(B_TOT / 32) * 2, 256, 0, stream>>>(
      x, var, s0, W1, b1, Wx, Wh, W2, b2, Hout, Pws);
  mminet_mlp<<<B_TOT / 16, 256, 0, stream>>>(
      var, amps, Wm1, bm1, Wm2, bm2, Wm3, bm3, Pws, out2);
}

// Round 13
// 294.001 us; speedup vs baseline: 1.3506x; 1.1327x over previous
//
#include <hip/hip_runtime.h>

#define B_TOT 4096
#define S_LEN 1024
#define HID 30
#define SKIP 16
#define HLEN (S_LEN - SKIP)   // 1008
#define WARM 32               // min h2 warm-up steps for non-first chunks

typedef float f32x16 __attribute__((ext_vector_type(16)));
typedef short bf16x8 __attribute__((ext_vector_type(8)));
typedef int   i32x4  __attribute__((ext_vector_type(4)));
typedef unsigned int u32x2 __attribute__((ext_vector_type(2)));

// ---- DPP helpers (epilogue red16 only) ----
template <int CTRL>
__device__ __forceinline__ float dppmov(float v) {
  return __int_as_float(__builtin_amdgcn_update_dpp(
      0, __float_as_int(v), CTRL, 0xF, 0xF, true));
}
template <int CTRL>
__device__ __forceinline__ float dpp_add(float v) { return v + dppmov<CTRL>(v); }
__device__ __forceinline__ float red16(float v) {
  v = dpp_add<0xB1>(v); v = dpp_add<0x4E>(v);
  v = dpp_add<0x141>(v); v = dpp_add<0x140>(v);
  return v;
}
__device__ __forceinline__ float sigmoid_fast(float z) {
  float e = __builtin_amdgcn_exp2f(z * -1.442695041f);
  return __builtin_amdgcn_rcpf(1.0f + e);
}
// v_cvt_pk_bf16_f32: two f32 -> one u32 of two bf16 (no builtin on gfx950)
__device__ __forceinline__ int cvt_pk_bf16(float a, float b) {
  int r; asm("v_cvt_pk_bf16_f32 %0, %1, %2" : "=v"(r) : "v"(a), "v"(b)); return r;
}
// split 8 f32 into hi/lo bf16 words (hi = bf16(v), lo = bf16(v - f32(hi)))
__device__ __forceinline__ void split8(const float* v, int* hw, int* lw) {
#pragma unroll
  for (int p = 0; p < 4; ++p) {
    int h = cvt_pk_bf16(v[2*p], v[2*p+1]);
    float f0 = __int_as_float(h << 16);
    float f1 = __int_as_float(h & 0xffff0000);
    lw[p] = cvt_pk_bf16(v[2*p] - f0, v[2*p+1] - f1);
    hw[p] = h;
  }
}
__device__ __forceinline__ bf16x8 frag4(const int* w) {
  return __builtin_bit_cast(bf16x8, (i32x4){w[0], w[1], w[2], w[3]});
}

// exchange lane l <-> l^32 and add (the two row-halves of one batch col)
__device__ __forceinline__ float redh(float v) {
#if __has_builtin(__builtin_amdgcn_permlane32_swap)
  unsigned iv = __float_as_uint(v);
  u32x2 qq = __builtin_amdgcn_permlane32_swap(iv, iv, false, false);
  return __uint_as_float(qq[0]) + __uint_as_float(qq[1]);
#else
  int l = (int)(threadIdx.x & 63);
  v += __int_as_float(__builtin_amdgcn_ds_bpermute(((l ^ 32) << 2),
                                                   __float_as_int(v)));
  return v;
#endif
}

// Time-chunked RNN scan, 32x32x16 MFMA, 32 batches/wave, 8 chunks/batch.
// Lesson ledger: (R1) VGPR cap >= live set; (R4) plain bf16 Wh.h fatal ->
// split-bf16 3-product; (R7) 16x16 MFMA verified; (R8/R11) 2 waves/SIMD
// co-residency unobtainable -> 1 wave/SIMD regime, minimize serial steps;
// (R12) 32x32 layout VERIFIED correct, but 6 parallel f32x16 accumulators
// + default 256-VGPR cap -> scratch spills (WRITE 17->32MB), 3390cyc/step.
// R13: C-operand-CHAINED MFMA accumulation (1 live acc, no vector adds)
// + __launch_bounds__(256,1) to unlock the 512-VGPR budget (we KNOW the
// kernel runs 1 wave/SIMD, so registers are free -- inverse of R1 lesson).
//
// Wave layout: batch col cb = lane&31, hi = lane>>5.
// D (m74/m101-verified): col=lane&31, row R(r)=(r&3)+8*(r>>2)+4*hi.
// k-unit maps shared by A and B (HW k-permutation cancels; verified for
// 16x16 in R7, for 32x32 by R12's passing absmax):
//   k-half 1 slot (j,hi) -> unit R(j);  k-half 2 -> unit 16+R(j).
// {R(0..7), 16+R(0..7)} == lane's D-row set -> sigmoid output feeds next
// step's B fragments ENTIRELY IN-LANE: B1=pack(hv[0..7]), B2=pack(hv[8..15]).
//
// Grid 256 scan-blocks: block = (group g = bid>>1, half = bid&1), 4 waves.
// Output boundaries: half0 {16,160,288,408,520}, half1 {520,648,776,900,
// 1024}. Non-first chunks: exact s1-only prescan [0,ps), ps=(ob-32)&~31,
// then 32-56 full warm-up steps (contraction ~0.35/step, err <1e-14;
// validated R2/R5/R6/R7/R9/R10/R11/R12).
__global__ __launch_bounds__(256, 1) void mminet_scan(
    const float* __restrict__ x,   const float* __restrict__ var,
    const float* __restrict__ s0,
    const float* __restrict__ W1,  const float* __restrict__ b1,
    const float* __restrict__ Wx,  const float* __restrict__ Wh,
    const float* __restrict__ W2,  const float* __restrict__ b2,
    float* __restrict__ Hout, float* __restrict__ Pws)
{
  __shared__ float Pred[4][32];

  const int tid   = threadIdx.x;
  const int l     = tid & 63;
  const int cl    = tid >> 6;                // local chunk / wave id (0..3)
  const int half  = blockIdx.x & 1;
  const int g     = blockIdx.x >> 1;         // batch group (32 batches)
  const int hi    = l >> 5;                  // row-half
  const int cb    = l & 31;                  // batch column
  const int b     = g * 32 + cb;

  const int ob = (half == 0)
      ? (cl == 0 ? 16  : cl == 1 ? 160 : cl == 2 ? 288 : 408)
      : (cl == 0 ? 520 : cl == 1 ? 648 : cl == 2 ? 776 : 900);
  const int oe = (half == 0)
      ? (cl == 0 ? 160 : cl == 1 ? 288 : cl == 2 ? 408 : 520)
      : (cl == 0 ? 648 : cl == 1 ? 776 : cl == 2 ? 900 : 1024);
  const bool first = (half == 0) && (cl == 0);
  const int ps = first ? SKIP : ((ob - WARM) & ~31);  // %32==0

  const float v0 = var[b*4+0], v1 = var[b*4+1], v2 = var[b*4+2], v3 = var[b*4+3];

  // ---- per-lane row constants for owned D-rows R(r) ----
  float wx0[16], wx1[16], wx2[16], cva[16], w1a[16], w2a[16], rc[16], s1[16];
#pragma unroll
  for (int r = 0; r < 16; ++r) {
    const int row = (r & 3) + 8 * (r >> 2) + 4 * hi;
    if (row < HID) {
      wx0[r] = Wx[row*7+0]; wx1[r] = Wx[row*7+1]; wx2[r] = Wx[row*7+2];
      cva[r] = Wx[row*7+3]*v0 + Wx[row*7+4]*v1 + Wx[row*7+5]*v2 + Wx[row*7+6]*v3;
      w1a[r] = W1[row]; w2a[r] = W2[row];
      rc[r]  = 5.0f * (float)(row + 1) / 30.0f;
      s1[r]  = s0[b*HID + row];
    } else {
      wx0[r]=wx1[r]=wx2[r]=cva[r]=w1a[r]=w2a[r]=s1[r]=0.f; rc[r]=1.0f;
    }
  }

  // ---- A fragments (Wh, split-bf16), row = cb, k-units R(j)/16+R(j) ----
  float a1v[8], a2v[8];
#pragma unroll
  for (int j = 0; j < 8; ++j) {
    const int u1 = (j & 3) + 8 * (j >> 2) + 4 * hi;   // 0..15
    const int u2 = 16 + u1;                           // 16..31
    a1v[j] = (cb < HID) ? Wh[cb*HID + u1] : 0.f;
    a2v[j] = (cb < HID && u2 < HID) ? Wh[cb*HID + u2] : 0.f;
  }
  int t0[4], t1[4], t2[4], t3[4];
  split8(a1v, t0, t1); split8(a2v, t2, t3);
  const bf16x8 A1h = frag4(t0), A1l = frag4(t1);
  const bf16x8 A2h = frag4(t2), A2l = frag4(t3);

  const float hcst = W1[30]*v0 + W1[31]*v1 + W1[32]*v2 + W1[33]*v3 + b1[0];
  const float hc2  = hcst + b2[0];

  float sw = 0.f;
#pragma unroll
  for (int r = 0; r < 16; ++r) sw += w2a[r];
  const float sumW2 = redh(sw);

  const float4* xb = (const float4*)(x + (size_t)b * S_LEN * 4);

  bf16x8 B1h, B1l, B2h, B2l;
  auto packB = [&](const float* hv) {
    int bh[4], bl[4];
    split8(hv, bh, bl);      B1h = frag4(bh); B1l = frag4(bl);
    split8(hv + 8, bh, bl);  B2h = frag4(bh); B2l = frag4(bl);
  };

  // one RNN step for 32 batches: 6 C-CHAINED 32x32x16 MFMAs (single live
  // f32x16 accumulator -- R13 fix for R12's spill collapse) + VALU
  auto dostep = [&](const float4 xq) -> float {
#pragma unroll
    for (int r = 0; r < 16; ++r)
      s1[r] = __builtin_amdgcn_fmed3f(s1[r] + xq.y, -rc[r], rc[r]);
    f32x16 acc;
#pragma unroll
    for (int r = 0; r < 16; ++r)
      acc[r] = cva[r] + wx0[r]*xq.x + wx1[r]*xq.z + wx2[r]*xq.w;
    acc = __builtin_amdgcn_mfma_f32_32x32x16_bf16(A1h, B1h, acc, 0, 0, 0);
    acc = __builtin_amdgcn_mfma_f32_32x32x16_bf16(A2h, B2h, acc, 0, 0, 0);
    acc = __builtin_amdgcn_mfma_f32_32x32x16_bf16(A1l, B1h, acc, 0, 0, 0);
    acc = __builtin_amdgcn_mfma_f32_32x32x16_bf16(A2l, B2h, acc, 0, 0, 0);
    acc = __builtin_amdgcn_mfma_f32_32x32x16_bf16(A1h, B1l, acc, 0, 0, 0);
    acc = __builtin_amdgcn_mfma_f32_32x32x16_bf16(A2h, B2l, acc, 0, 0, 0);
    float hv[16];
#pragma unroll
    for (int r = 0; r < 16; ++r) hv[r] = sigmoid_fast(acc[r]);
    packB(hv);                                 // B for NEXT step, in-lane
    float hp = 0.f;
#pragma unroll
    for (int r = 0; r < 16; ++r)
      hp = fmaf(w1a[r], s1[r], fmaf(w2a[r], hv[r], hp));
    return redh(hp);                           // + hc2 by caller
  };

  if (first) {
    // ---- t = 0 prologue (exact reference init) ----
    float4 xv = xb[0];
#pragma unroll
    for (int r = 0; r < 16; ++r)
      s1[r] = __builtin_amdgcn_fmed3f(s1[r] + xv.y, -rc[r], rc[r]);
    float hh = 0.f;
#pragma unroll
    for (int r = 0; r < 16; ++r) hh = fmaf(w1a[r], s1[r], hh);
    const float Hh0  = redh(hh) + hcst;
    const float hpre = (xv.x - Hh0) / sumW2;   // uniform initial h2
    float hv[16];
#pragma unroll
    for (int r = 0; r < 16; ++r) {
      const int row = (r & 3) + 8 * (r >> 2) + 4 * hi;
      float rs = 0.f;
      if (row < HID)
        for (int u = 0; u < HID; ++u) rs += Wh[row*HID + u];
      float z = cva[r] + wx0[r]*xv.x + wx1[r]*xv.z + wx2[r]*xv.w + rs*hpre;
      hv[r] = sigmoid_fast(z);
    }
    packB(hv);
    // ---- t = 1..15 : recurrence only ----
    for (int t = 1; t < SKIP; ++t) (void)dostep(xb[t]);
  } else {
    // ---- s1-only exact prescan over [0, ps): 32-deep pipelined ----
    const float* xf = x + (size_t)b * S_LEN * 4;
    float dc[32], dn[32];
#pragma unroll
    for (int u = 0; u < 32; ++u) dc[u] = xf[u*4 + 1];
    for (int t = 0; t < ps; t += 32) {
      const bool more = (t + 32 < ps);          // wave-uniform
      if (more) {
#pragma unroll
        for (int u = 0; u < 32; ++u) dn[u] = xf[(t + 32 + u)*4 + 1];
      }
#pragma unroll
      for (int u = 0; u < 32; ++u) {
#pragma unroll
        for (int r = 0; r < 16; ++r)
          s1[r] = __builtin_amdgcn_fmed3f(s1[r] + dc[u], -rc[r], rc[r]);
      }
      if (more) {
#pragma unroll
        for (int u = 0; u < 32; ++u) dc[u] = dn[u];
      }
    }
    // h2 warm-up handled by the unified loop below (t in [ps, ob))
    float hv[16];
#pragma unroll
    for (int r = 0; r < 16; ++r) hv[r] = 0.5f;
    packB(hv);
  }

  // ==== unified warm+output loop: t in [ps, oe), 4-block, 4-deep
  // prefetch (proven R10/R11/R12). P pairs only for s >= ob and s > SKIP;
  // stores only when t >= ob (block-uniform; ps, ob both %4==0).
  float P = 0.f, Hprev = 0.f, Bprev = 0.f;
  float4 xc0 = xb[ps+0], xc1 = xb[ps+1], xc2 = xb[ps+2], xc3 = xb[ps+3];

  for (int t = ps; t < oe; t += 4) {
    const int tn = (t + 4 < oe) ? (t + 4) : t;  // uniform
    float4 xn0 = xb[tn+0], xn1 = xb[tn+1], xn2 = xb[tn+2], xn3 = xb[tn+3];

    float hq0, hq1, hq2, hq3;
    {
      float Ht = dostep(xc0) + hc2;
      if (t + 0 > SKIP && t + 0 >= ob) P += (xc0.x - Bprev) * (Ht + Hprev);
      Hprev = Ht; Bprev = xc0.x; hq0 = Ht;
    }
    {
      float Ht = dostep(xc1) + hc2;
      if (t + 1 > SKIP && t + 1 >= ob) P += (xc1.x - Bprev) * (Ht + Hprev);
      Hprev = Ht; Bprev = xc1.x; hq1 = Ht;
    }
    {
      float Ht = dostep(xc2) + hc2;
      if (t + 2 > SKIP && t + 2 >= ob) P += (xc2.x - Bprev) * (Ht + Hprev);
      Hprev = Ht; Bprev = xc2.x; hq2 = Ht;
    }
    {
      float Ht = dostep(xc3) + hc2;
      if (t + 3 > SKIP && t + 3 >= ob) P += (xc3.x - Bprev) * (Ht + Hprev);
      Hprev = Ht; Bprev = xc3.x; hq3 = Ht;
    }
    if (t >= ob && l < 32) {                   // hi==0 lane stores batch cb
      *(float4*)(Hout + (size_t)b * HLEN + (t - SKIP)) =
          make_float4(hq0, hq1, hq2, hq3);
    }
    xc0 = xn0; xc1 = xn1; xc2 = xn2; xc3 = xn3;
  }

  // ---- per-block P reduction -> workspace (both slots overwritten) ----
  if (l < 32) Pred[cl][cb] = P;
  __syncthreads();
  if (tid < 32) {
    const int bb = g * 32 + tid;
    Pws[bb * 2 + half] =
        Pred[0][tid] + Pred[1][tid] + Pred[2][tid] + Pred[3][tid];
  }
}

// ==== epilogue kernel: 16 groups of 16 lanes per block, one batch each ====
__global__ __launch_bounds__(256) void mminet_mlp(
    const float* __restrict__ var, const float* __restrict__ amps,
    const float* __restrict__ Wm1, const float* __restrict__ bm1,
    const float* __restrict__ Wm2, const float* __restrict__ bm2,
    const float* __restrict__ Wm3, const float* __restrict__ bm3,
    const float* __restrict__ Pws, float* __restrict__ out2)
{
  __shared__ float mlpbuf[16][64];
  const int tid = threadIdx.x;
  const int li  = tid & 15;
  const int g   = tid >> 4;                    // 0..15
  const int be  = blockIdx.x * 16 + g;

  const float Ptot = Pws[be*2 + 0] + Pws[be*2 + 1];
  const float e0 = var[be*4+0], e1 = var[be*4+1], e2 = var[be*4+2], e3 = var[be*4+3];
  const float am0 = amps[be*2+0], am1 = amps[be*2+1];

  float Pp = Ptot * 0.5f * am0 * am1;
  Pp *= __builtin_amdgcn_exp2f(e0 * 3.321928095f);     // * 10^var0
  Pp = fmaxf(Pp, 1e-12f);
  const float Pcv = __builtin_amdgcn_logf(Pp) * 0.30102999566f;  // log10

  float* hs = &mlpbuf[g][0];
#pragma unroll
  for (int qq = 0; qq < 4; ++qq) {
    const int n = li + 16 * qq;
    const float* wr = Wm1 + n * 5;
    float h1v = bm1[n] + wr[0]*e0 + wr[1]*e1 + wr[2]*e2 + wr[3]*e3 + wr[4]*Pcv;
    hs[n] = fmaxf(h1v, 0.f);                   // wave-synchronous in group
  }
  const int m0 = li, m1 = li + 16;
  const float4* h1v4 = (const float4*)hs;
  const float4* w2a4 = (const float4*)(Wm2 + m0 * 64);
  const float4* w2b4 = (const float4*)(Wm2 + m1 * 64);
  float zz0 = bm2[m0], zz1 = bm2[m1];
#pragma unroll
  for (int qq = 0; qq < 16; ++qq) {
    float4 hh = h1v4[qq];
    float4 wa = w2a4[qq], wb = w2b4[qq];
    zz0 += wa.x*hh.x + wa.y*hh.y + wa.z*hh.z + wa.w*hh.w;
    zz1 += wb.x*hh.x + wb.y*hh.y + wb.z*hh.z + wb.w*hh.w;
  }
  float sp = Wm3[m0] * fmaxf(zz0, 0.f) + Wm3[m1] * fmaxf(zz1, 0.f);
  sp = red16(sp);
  if (li == 0) out2[be] = Pcv + sp + bm3[0];
}

extern "C" void kernel_launch(void* const* d_in, const int* in_sizes, int n_in,
                              void* d_out, int out_size, void* d_ws, size_t ws_size,
                              hipStream_t stream)
{
  const float* x    = (const float*)d_in[0];
  const float* var  = (const float*)d_in[1];
  const float* amps = (const float*)d_in[2];
  const float* s0   = (const float*)d_in[3];
  const float* W1   = (const float*)d_in[4];
  const float* b1   = (const float*)d_in[5];
  const float* Wx   = (const float*)d_in[6];
  const float* Wh   = (const float*)d_in[7];
  const float* W2   = (const float*)d_in[8];
  const float* b2   = (const float*)d_in[9];
  const float* Wm1  = (const float*)d_in[10];
  const float* bm1  = (const float*)d_in[11];
  const float* Wm2  = (const float*)d_in[12];
  const float* bm2  = (const float*)d_in[13];
  const float* Wm3  = (const float*)d_in[14];
  const float* bm3  = (const float*)d_in[15];
  // d_in[16] = n_init (compile-time 16)

  float* Hout = (float*)d_out;
  float* out2 = (float*)d_out + (size_t)B_TOT * HLEN;
  float* Pws  = (float*)d_ws;                  // 4096*2 floats = 32 KB

  mminet_scan<<<(B_TOT / 32) * 2, 256, 0, stream>>>(
      x, var, s0, W1, b1, Wx, Wh, W2, b2, Hout, Pws);
  mminet_mlp<<<B_TOT / 16, 256, 0, stream>>>(
      var, amps, Wm1, bm1, Wm2, bm2, Wm3, bm3, Pws, out2);
}

// Round 14
// 289.036 us; speedup vs baseline: 1.3738x; 1.0172x over previous
//
#include <hip/hip_runtime.h>

#define B_TOT 4096
#define S_LEN 1024
#define HID 30
#define SKIP 16
#define HLEN (S_LEN - SKIP)   // 1008
#define WARM 32               // min h2 warm-up steps for non-first chunks

typedef float f32x16 __attribute__((ext_vector_type(16)));
typedef short bf16x8 __attribute__((ext_vector_type(8)));
typedef int   i32x4  __attribute__((ext_vector_type(4)));
typedef unsigned int u32x2 __attribute__((ext_vector_type(2)));

// ---- DPP helpers (epilogue red16 only) ----
template <int CTRL>
__device__ __forceinline__ float dppmov(float v) {
  return __int_as_float(__builtin_amdgcn_update_dpp(
      0, __float_as_int(v), CTRL, 0xF, 0xF, true));
}
template <int CTRL>
__device__ __forceinline__ float dpp_add(float v) { return v + dppmov<CTRL>(v); }
__device__ __forceinline__ float red16(float v) {
  v = dpp_add<0xB1>(v); v = dpp_add<0x4E>(v);
  v = dpp_add<0x141>(v); v = dpp_add<0x140>(v);
  return v;
}
__device__ __forceinline__ float sigmoid_fast(float z) {
  float e = __builtin_amdgcn_exp2f(z * -1.442695041f);
  return __builtin_amdgcn_rcpf(1.0f + e);
}
// v_cvt_pk_bf16_f32: two f32 -> one u32 of two bf16 (no builtin on gfx950)
__device__ __forceinline__ int cvt_pk_bf16(float a, float b) {
  int r; asm("v_cvt_pk_bf16_f32 %0, %1, %2" : "=v"(r) : "v"(a), "v"(b)); return r;
}
// split 8 f32 into hi/lo bf16 words (hi = bf16(v), lo = bf16(v - f32(hi)))
__device__ __forceinline__ void split8(const float* v, int* hw, int* lw) {
#pragma unroll
  for (int p = 0; p < 4; ++p) {
    int h = cvt_pk_bf16(v[2*p], v[2*p+1]);
    float f0 = __int_as_float(h << 16);
    float f1 = __int_as_float(h & 0xffff0000);
    lw[p] = cvt_pk_bf16(v[2*p] - f0, v[2*p+1] - f1);
    hw[p] = h;
  }
}
__device__ __forceinline__ bf16x8 frag4(const int* w) {
  return __builtin_bit_cast(bf16x8, (i32x4){w[0], w[1], w[2], w[3]});
}

// exchange lane l <-> l^32 and add (the two row-halves of one batch col)
__device__ __forceinline__ float redh(float v) {
#if __has_builtin(__builtin_amdgcn_permlane32_swap)
  unsigned iv = __float_as_uint(v);
  u32x2 qq = __builtin_amdgcn_permlane32_swap(iv, iv, false, false);
  return __uint_as_float(qq[0]) + __uint_as_float(qq[1]);
#else
  int l = (int)(threadIdx.x & 63);
  v += __int_as_float(__builtin_amdgcn_ds_bpermute(((l ^ 32) << 2),
                                                   __float_as_int(v)));
  return v;
#endif
}

// Time-chunked RNN scan, 32x32x16 MFMA, 32 batches/wave, 8 chunks/batch.
// Lesson ledger: (R1) VGPR cap >= live set; (R4) plain bf16 Wh.h fatal ->
// split-bf16 3-product; (R8/R11) 2 waves/SIMD unobtainable -> 1 wave/SIMD,
// minimize serial steps + step latency; (R12) 32x32 layout verified;
// (R13) chained acc helped but VGPR still 256 + 9MB scratch: live set
// (128 consts + 64 prescan bufs + frags + prefetch) > 256.
// R14: (a) fold wx0/wx1 into MFMA spare k-units 30/31 (A2 slots 6,7 of
// hi=1 = wx0,wx1; B slots = next-x injected into dummy-row hv[14],hv[15])
// -> -32 regs, -32 fma/step; (b) prescan bufs 32->8-deep (-48 regs;
// processing 512cyc/block hides ~400cyc latency anyway); (c) chunk spans
// rebalanced for prescan issue cost (64cyc/t vs ~650cyc/step).
//
// Wave layout: batch col cb = lane&31, hi = lane>>5.
// D (m74/m101-verified): col=lane&31, row R(r)=(r&3)+8*(r>>2)+4*hi.
// k-unit map shared by A and B (HW permutation cancels; R12-verified):
//   k-half1 slot (j,hi) -> unit u1(j)=(j&3)+8*(j>>2)+4hi; k-half2 -> 16+u1.
// {R(0..7),16+R(0..7)} == lane's D-row set -> h feeds next step's B
// IN-LANE. Units 30,31 (hi=1 slots 6,7 of half2) carry the x-terms.
//
// Grid 256 scan-blocks: block = (group g = bid>>1, half = bid&1), 4 waves.
// Output boundaries {16,188,340,484,608,728,832,932,1024} (spans %4==0,
// balanced vs prescan length). Non-first chunks: exact s1-only prescan
// [0,ps), ps=(ob-32)&~31, then 32-60 warm-up steps (contraction
// ~0.35/step, err <1e-14; validated R2..R13).
__global__ __launch_bounds__(256, 1) void mminet_scan(
    const float* __restrict__ x,   const float* __restrict__ var,
    const float* __restrict__ s0,
    const float* __restrict__ W1,  const float* __restrict__ b1,
    const float* __restrict__ Wx,  const float* __restrict__ Wh,
    const float* __restrict__ W2,  const float* __restrict__ b2,
    float* __restrict__ Hout, float* __restrict__ Pws)
{
  __shared__ float Pred[4][32];

  const int tid   = threadIdx.x;
  const int l     = tid & 63;
  const int cl    = tid >> 6;                // local chunk / wave id (0..3)
  const int half  = blockIdx.x & 1;
  const int g     = blockIdx.x >> 1;         // batch group (32 batches)
  const int hi    = l >> 5;                  // row-half
  const int cb    = l & 31;                  // batch column
  const int b     = g * 32 + cb;

  const int ob = (half == 0)
      ? (cl == 0 ? 16  : cl == 1 ? 188 : cl == 2 ? 340 : 484)
      : (cl == 0 ? 608 : cl == 1 ? 728 : cl == 2 ? 832 : 932);
  const int oe = (half == 0)
      ? (cl == 0 ? 188 : cl == 1 ? 340 : cl == 2 ? 484 : 608)
      : (cl == 0 ? 728 : cl == 1 ? 832 : cl == 2 ? 932 : 1024);
  const bool first = (half == 0) && (cl == 0);
  const int ps = first ? SKIP : ((ob - WARM) & ~31);  // %32==0

  const float v0 = var[b*4+0], v1 = var[b*4+1], v2 = var[b*4+2], v3 = var[b*4+3];

  // ---- per-lane row constants for owned D-rows R(r) ----
  // (wx0/wx1 folded into MFMA -- only wx2 stays on VALU)
  float wx2[16], cva[16], w1a[16], w2a[16], rc[16], s1[16];
#pragma unroll
  for (int r = 0; r < 16; ++r) {
    const int row = (r & 3) + 8 * (r >> 2) + 4 * hi;
    if (row < HID) {
      wx2[r] = Wx[row*7+2];
      cva[r] = Wx[row*7+3]*v0 + Wx[row*7+4]*v1 + Wx[row*7+5]*v2 + Wx[row*7+6]*v3;
      w1a[r] = W1[row]; w2a[r] = W2[row];
      rc[r]  = 5.0f * (float)(row + 1) / 30.0f;
      s1[r]  = s0[b*HID + row];
    } else {
      wx2[r]=cva[r]=w1a[r]=w2a[r]=s1[r]=0.f; rc[r]=1.0f;
    }
  }

  // ---- A fragments (Wh + folded Wx cols 0,1; split-bf16) ----
  float a1v[8], a2v[8];
#pragma unroll
  for (int j = 0; j < 8; ++j) {
    const int u1 = (j & 3) + 8 * (j >> 2) + 4 * hi;   // 0..15
    const int u2 = 16 + u1;                           // 16..31
    a1v[j] = (cb < HID) ? Wh[cb*HID + u1] : 0.f;
    a2v[j] = (cb < HID && u2 < HID) ? Wh[cb*HID + u2] : 0.f;
  }
  if (hi) {   // units 30,31 carry the x-coupling: A[i][30]=wx0[i], [31]=wx1[i]
    a2v[6] = (cb < HID) ? Wx[cb*7+0] : 0.f;
    a2v[7] = (cb < HID) ? Wx[cb*7+1] : 0.f;
  }
  int t0[4], t1[4], t2[4], t3[4];
  split8(a1v, t0, t1); split8(a2v, t2, t3);
  const bf16x8 A1h = frag4(t0), A1l = frag4(t1);
  const bf16x8 A2h = frag4(t2), A2l = frag4(t3);

  const float hcst = W1[30]*v0 + W1[31]*v1 + W1[32]*v2 + W1[33]*v3 + b1[0];
  const float hc2  = hcst + b2[0];

  float sw = 0.f;
#pragma unroll
  for (int r = 0; r < 16; ++r) sw += w2a[r];
  const float sumW2 = redh(sw);

  const float4* xb = (const float4*)(x + (size_t)b * S_LEN * 4);

  bf16x8 B1h, B1l, B2h, B2l;
  auto packB = [&](const float* hv) {
    int bh[4], bl[4];
    split8(hv, bh, bl);      B1h = frag4(bh); B1l = frag4(bl);
    split8(hv + 8, bh, bl);  B2h = frag4(bh); B2l = frag4(bl);
  };

  // one RNN step for 32 batches: 6 C-chained 32x32x16 MFMAs + VALU.
  // xn = NEXT step's x (injected into B units 30,31 via dummy-row slots).
  auto dostep = [&](const float4 xq, const float4 xn) -> float {
#pragma unroll
    for (int r = 0; r < 16; ++r)
      s1[r] = __builtin_amdgcn_fmed3f(s1[r] + xq.y, -rc[r], rc[r]);
    f32x16 acc;
#pragma unroll
    for (int r = 0; r < 16; ++r)
      acc[r] = fmaf(wx2[r], xq.w, cva[r]);
    acc = __builtin_amdgcn_mfma_f32_32x32x16_bf16(A1h, B1h, acc, 0, 0, 0);
    acc = __builtin_amdgcn_mfma_f32_32x32x16_bf16(A2h, B2h, acc, 0, 0, 0);
    acc = __builtin_amdgcn_mfma_f32_32x32x16_bf16(A1l, B1h, acc, 0, 0, 0);
    acc = __builtin_amdgcn_mfma_f32_32x32x16_bf16(A2l, B2h, acc, 0, 0, 0);
    acc = __builtin_amdgcn_mfma_f32_32x32x16_bf16(A1h, B1l, acc, 0, 0, 0);
    acc = __builtin_amdgcn_mfma_f32_32x32x16_bf16(A2h, B2l, acc, 0, 0, 0);
    float hv[16];
#pragma unroll
    for (int r = 0; r < 16; ++r) hv[r] = sigmoid_fast(acc[r]);
    float hp = 0.f;
#pragma unroll
    for (int r = 0; r < 16; ++r)
      hp = fmaf(w1a[r], s1[r], fmaf(w2a[r], hv[r], hp));
    if (hi) { hv[14] = xn.x; hv[15] = xn.z; }  // dummy rows -> x-injection
    packB(hv);                                 // B for NEXT step, in-lane
    return redh(hp);                           // + hc2 by caller
  };

  if (first) {
    // ---- t = 0 prologue (exact reference init) ----
    float4 xv = xb[0];
    float4 x1 = xb[1];
#pragma unroll
    for (int r = 0; r < 16; ++r)
      s1[r] = __builtin_amdgcn_fmed3f(s1[r] + xv.y, -rc[r], rc[r]);
    float hh = 0.f;
#pragma unroll
    for (int r = 0; r < 16; ++r) hh = fmaf(w1a[r], s1[r], hh);
    const float Hh0  = redh(hh) + hcst;
    const float hpre = (xv.x - Hh0) / sumW2;   // uniform initial h2
    float hv[16];
#pragma unroll
    for (int r = 0; r < 16; ++r) {
      const int row = (r & 3) + 8 * (r >> 2) + 4 * hi;
      float rs = 0.f, w0 = 0.f, w1x = 0.f;
      if (row < HID) {
        for (int u = 0; u < HID; ++u) rs += Wh[row*HID + u];
        w0 = Wx[row*7+0]; w1x = Wx[row*7+1];
      }
      float z = cva[r] + w0*xv.x + w1x*xv.z + wx2[r]*xv.w + rs*hpre;
      hv[r] = sigmoid_fast(z);
    }
    if (hi) { hv[14] = x1.x; hv[15] = x1.z; }
    packB(hv);
    // ---- t = 1..15 : recurrence only ----
    for (int t = 1; t < SKIP; ++t) (void)dostep(xb[t], xb[t + 1]);
  } else {
    // ---- s1-only exact prescan over [0, ps): 8-deep pipelined ----
    // (8 d-values = 512 cyc of processing >> ~400 cyc load latency)
    const float* xf = x + (size_t)b * S_LEN * 4;
    float dc[8], dn[8];
#pragma unroll
    for (int u = 0; u < 8; ++u) dc[u] = xf[u*4 + 1];
    for (int t = 0; t < ps; t += 8) {
      const bool more = (t + 8 < ps);           // wave-uniform
      if (more) {
#pragma unroll
        for (int u = 0; u < 8; ++u) dn[u] = xf[(t + 8 + u)*4 + 1];
      }
#pragma unroll
      for (int u = 0; u < 8; ++u) {
#pragma unroll
        for (int r = 0; r < 16; ++r)
          s1[r] = __builtin_amdgcn_fmed3f(s1[r] + dc[u], -rc[r], rc[r]);
      }
      if (more) {
#pragma unroll
        for (int u = 0; u < 8; ++u) dc[u] = dn[u];
      }
    }
    // h2 warm-up handled by the unified loop below (t in [ps, ob))
    float hv[16];
#pragma unroll
    for (int r = 0; r < 16; ++r) hv[r] = 0.5f;
    if (hi) { float4 x0 = xb[ps]; hv[14] = x0.x; hv[15] = x0.z; }
    packB(hv);
  }

  // ==== unified warm+output loop: t in [ps, oe), 4-block, 4-deep
  // prefetch. P pairs only for s >= ob and s > SKIP; stores only when
  // t >= ob (block-uniform; ps, ob both %4==0).
  float P = 0.f, Hprev = 0.f, Bprev = 0.f;
  float4 xc0 = xb[ps+0], xc1 = xb[ps+1], xc2 = xb[ps+2], xc3 = xb[ps+3];

  for (int t = ps; t < oe; t += 4) {
    const int tn = (t + 4 < oe) ? (t + 4) : t;  // uniform
    float4 xn0 = xb[tn+0], xn1 = xb[tn+1], xn2 = xb[tn+2], xn3 = xb[tn+3];

    float hq0, hq1, hq2, hq3;
    {
      float Ht = dostep(xc0, xc1) + hc2;
      if (t + 0 > SKIP && t + 0 >= ob) P += (xc0.x - Bprev) * (Ht + Hprev);
      Hprev = Ht; Bprev = xc0.x; hq0 = Ht;
    }
    {
      float Ht = dostep(xc1, xc2) + hc2;
      if (t + 1 > SKIP && t + 1 >= ob) P += (xc1.x - Bprev) * (Ht + Hprev);
      Hprev = Ht; Bprev = xc1.x; hq1 = Ht;
    }
    {
      float Ht = dostep(xc2, xc3) + hc2;
      if (t + 2 > SKIP && t + 2 >= ob) P += (xc2.x - Bprev) * (Ht + Hprev);
      Hprev = Ht; Bprev = xc2.x; hq2 = Ht;
    }
    {
      float Ht = dostep(xc3, xn0) + hc2;   // last step of chunk: xn unused
      if (t + 3 > SKIP && t + 3 >= ob) P += (xc3.x - Bprev) * (Ht + Hprev);
      Hprev = Ht; Bprev = xc3.x; hq3 = Ht;
    }
    if (t >= ob && l < 32) {                   // hi==0 lane stores batch cb
      *(float4*)(Hout + (size_t)b * HLEN + (t - SKIP)) =
          make_float4(hq0, hq1, hq2, hq3);
    }
    xc0 = xn0; xc1 = xn1; xc2 = xn2; xc3 = xn3;
  }

  // ---- per-block P reduction -> workspace (both slots overwritten) ----
  if (l < 32) Pred[cl][cb] = P;
  __syncthreads();
  if (tid < 32) {
    const int bb = g * 32 + tid;
    Pws[bb * 2 + half] =
        Pred[0][tid] + Pred[1][tid] + Pred[2][tid] + Pred[3][tid];
  }
}

// ==== epilogue kernel: 16 groups of 16 lanes per block, one batch each ====
__global__ __launch_bounds__(256) void mminet_mlp(
    const float* __restrict__ var, const float* __restrict__ amps,
    const float* __restrict__ Wm1, const float* __restrict__ bm1,
    const float* __restrict__ Wm2, const float* __restrict__ bm2,
    const float* __restrict__ Wm3, const float* __restrict__ bm3,
    const float* __restrict__ Pws, float* __restrict__ out2)
{
  __shared__ float mlpbuf[16][64];
  const int tid = threadIdx.x;
  const int li  = tid & 15;
  const int g   = tid >> 4;                    // 0..15
  const int be  = blockIdx.x * 16 + g;

  const float Ptot = Pws[be*2 + 0] + Pws[be*2 + 1];
  const float e0 = var[be*4+0], e1 = var[be*4+1], e2 = var[be*4+2], e3 = var[be*4+3];
  const float am0 = amps[be*2+0], am1 = amps[be*2+1];

  float Pp = Ptot * 0.5f * am0 * am1;
  Pp *= __builtin_amdgcn_exp2f(e0 * 3.321928095f);     // * 10^var0
  Pp = fmaxf(Pp, 1e-12f);
  const float Pcv = __builtin_amdgcn_logf(Pp) * 0.30102999566f;  // log10

  float* hs = &mlpbuf[g][0];
#pragma unroll
  for (int qq = 0; qq < 4; ++qq) {
    const int n = li + 16 * qq;
    const float* wr = Wm1 + n * 5;
    float h1v = bm1[n] + wr[0]*e0 + wr[1]*e1 + wr[2]*e2 + wr[3]*e3 + wr[4]*Pcv;
    hs[n] = fmaxf(h1v, 0.f);                   // wave-synchronous in group
  }
  const int m0 = li, m1 = li + 16;
  const float4* h1v4 = (const float4*)hs;
  const float4* w2a4 = (const float4*)(Wm2 + m0 * 64);
  const float4* w2b4 = (const float4*)(Wm2 + m1 * 64);
  float zz0 = bm2[m0], zz1 = bm2[m1];
#pragma unroll
  for (int qq = 0; qq < 16; ++qq) {
    float4 hh = h1v4[qq];
    float4 wa = w2a4[qq], wb = w2b4[qq];
    zz0 += wa.x*hh.x + wa.y*hh.y + wa.z*hh.z + wa.w*hh.w;
    zz1 += wb.x*hh.x + wb.y*hh.y + wb.z*hh.z + wb.w*hh.w;
  }
  float sp = Wm3[m0] * fmaxf(zz0, 0.f) + Wm3[m1] * fmaxf(zz1, 0.f);
  sp = red16(sp);
  if (li == 0) out2[be] = Pcv + sp + bm3[0];
}

extern "C" void kernel_launch(void* const* d_in, const int* in_sizes, int n_in,
                              void* d_out, int out_size, void* d_ws, size_t ws_size,
                              hipStream_t stream)
{
  const float* x    = (const float*)d_in[0];
  const float* var  = (const float*)d_in[1];
  const float* amps = (const float*)d_in[2];
  const float* s0   = (const float*)d_in[3];
  const float* W1   = (const float*)d_in[4];
  const float* b1   = (const float*)d_in[5];
  const float* Wx   = (const float*)d_in[6];
  const float* Wh   = (const float*)d_in[7];
  const float* W2   = (const float*)d_in[8];
  const float* b2   = (const float*)d_in[9];
  const float* Wm1  = (const float*)d_in[10];
  const float* bm1  = (const float*)d_in[11];
  const float* Wm2  = (const float*)d_in[12];
  const float* bm2  = (const float*)d_in[13];
  const float* Wm3  = (const float*)d_in[14];
  const float* bm3  = (const float*)d_in[15];
  // d_in[16] = n_init (compile-time 16)

  float* Hout = (float*)d_out;
  float* out2 = (float*)d_out + (size_t)B_TOT * HLEN;
  float* Pws  = (float*)d_ws;                  // 4096*2 floats = 32 KB

  mminet_scan<<<(B_TOT / 32) * 2, 256, 0, stream>>>(
      x, var, s0, W1, b1, Wx, Wh, W2, b2, Hout, Pws);
  mminet_mlp<<<B_TOT / 16, 256, 0, stream>>>(
      var, amps, Wm1, bm1, Wm2, bm2, Wm3, bm3, Pws, out2);
}